// Round 3
// baseline (473.269 us; speedup 1.0000x reference)
//
#include <hip/hip_runtime.h>
#include <hip/hip_bf16.h>

// ChebyshevKANLayer: y[b,o] = sum_{i,j} T_j(xhat[b,i]) * C[i,o,j]
// R3 structure: degree padded 9->16 (Ktil = 1024*16 = 16384), A-tile built
// ON THE FLY in the GEMM from xnT (transposed normalized x, fp32), split-K x2,
// XCD-aware swizzle. A never touches HBM.
//
// ws: [0,64K) stats | [+32MB) xnT fp32 [1024][8192] | [+33.5MB) Bpad bf16
//     [o][i*16+j] | [+67MB) partials fp32 [2][8192][1024]

typedef __attribute__((ext_vector_type(8))) short bf16x8s;   // MFMA A/B frag (4 VGPRs)
typedef __attribute__((ext_vector_type(4))) float f32x4;     // MFMA C/D frag

constexpr int BROWS = 8192;
constexpr int IDIM  = 1024;
constexpr int ODIM  = 1024;
constexpr int DEG1  = 9;
constexpr int KP    = 16;           // padded k-slots per input i (slots 9..15 are zero)
constexpr int KTIL  = IDIM * KP;    // 16384

__device__ __forceinline__ ushort f2bf(float f) {
  return ((__hip_bfloat16_raw)__float2bfloat16(f)).x;
}

// async global->LDS, 16 B per lane. LDS dst MUST be wave-uniform base + lane*16.
__device__ __forceinline__ void gload_lds16(const void* g, void* l) {
  __builtin_amdgcn_global_load_lds(
      (const __attribute__((address_space(1))) unsigned int*)g,
      (__attribute__((address_space(3))) unsigned int*)l, 16, 0, 0);
}

// ---------- 1. per-row min/max -> (scale, offset):  xhat = scale*x + offset ----------
__global__ __launch_bounds__(256) void rowstats_kernel(const float* __restrict__ x,
                                                       float* __restrict__ stats) {
  const int row  = blockIdx.x * 4 + (threadIdx.x >> 6);   // one wave per row
  const int lane = threadIdx.x & 63;
  const float4* xr = (const float4*)(x + (size_t)row * IDIM);
  float mn = 3.402823466e38f, mx = -3.402823466e38f;
#pragma unroll
  for (int c = 0; c < 4; ++c) {
    float4 v = xr[lane + c * 64];
    mn = fminf(mn, fminf(fminf(v.x, v.y), fminf(v.z, v.w)));
    mx = fmaxf(mx, fmaxf(fmaxf(v.x, v.y), fmaxf(v.z, v.w)));
  }
#pragma unroll
  for (int off = 32; off >= 1; off >>= 1) {
    mn = fminf(mn, __shfl_xor(mn, off));
    mx = fmaxf(mx, __shfl_xor(mx, off));
  }
  if (lane == 0) {
    float inv = 2.0f / (mx - mn);
    stats[row * 2 + 0] = inv;                 // scale
    stats[row * 2 + 1] = -mn * inv - 1.0f;    // offset
  }
}

// ---------- 2. xnT[i][r] = scale[r]*x[r][i]+offset[r], 64x64 LDS transpose tile ----------
__global__ __launch_bounds__(256) void transpose_norm_kernel(const float* __restrict__ x,
                                                             const float* __restrict__ stats,
                                                             float* __restrict__ xnT) {
  __shared__ float tile[64][65];               // +1 pad: conflict-free transpose
  const int i0 = blockIdx.x * 64;
  const int r0 = blockIdx.y * 64;
  const int t  = threadIdx.x;
  const int lc = t & 63;                       // lane-contiguous dim
  const int p4 = t >> 6;                       // 0..3
#pragma unroll
  for (int rr = p4; rr < 64; rr += 4) {        // read: lanes vary i -> coalesced
    const float sc = stats[(r0 + rr) * 2 + 0];
    const float of = stats[(r0 + rr) * 2 + 1];
    tile[rr][lc] = fmaf(sc, x[(size_t)(r0 + rr) * IDIM + i0 + lc], of);
  }
  __syncthreads();
#pragma unroll
  for (int ii = p4; ii < 64; ii += 4)          // write: lanes vary r -> coalesced
    xnT[(size_t)(i0 + ii) * BROWS + r0 + lc] = tile[lc][ii];
}

// ---------- 3. Bpad[o][i*16+j] = coeffs[i][o][j] (j<9) else 0; bf16 ----------
// tile: 16 i x 64 o. Coalesced float reads, coalesced uint4 writes.
__global__ __launch_bounds__(256) void build_b_kernel(const float* __restrict__ coeffs,
                                                      ushort* __restrict__ Bp) {
  __shared__ __align__(16) ushort tile[64 * 256];          // 32 KB [o_l][i_l*16+j]
  const int i0 = blockIdx.x * 16;
  const int o0 = blockIdx.y * 64;
  const int t  = threadIdx.x;
  uint4* tl4 = (uint4*)tile;
#pragma unroll
  for (int c = 0; c < 8; ++c) tl4[c * 256 + t] = (uint4){0, 0, 0, 0};  // zero pad slots
  __syncthreads();
  for (int idx = t; idx < 16 * 576; idx += 256) {          // 576 = 64 o * 9 j
    const int i_l = idx / 576;
    const int rem = idx - i_l * 576;                       // = o_l*9 + j
    const int o_l = rem / 9;
    const int j   = rem - o_l * 9;
    const float v = coeffs[((size_t)(i0 + i_l) * ODIM + o0) * DEG1 + rem];
    tile[o_l * 256 + i_l * KP + j] = f2bf(v);
  }
  __syncthreads();
  for (int idx = t; idx < 64 * 32; idx += 256) {           // 32 uint4 per o-row
    const int o_l = idx >> 5;
    const int w   = idx & 31;
    uint4* gdst = (uint4*)(Bp + (size_t)(o0 + o_l) * KTIL + i0 * KP);
    gdst[w] = tl4[idx];
  }
}

// ---------- 4. fused GEMM: 128x128 tile, BK=32 (=2 i), split-K x2, XCD swizzle ----------
// A-tile computed in-kernel: thread t owns (r = t&127, il = t>>7), runs the Chebyshev
// recurrence in fp32 and ds_writes 16 bf16 slots (9 real + 7 zero) per iter.
__global__ __launch_bounds__(256, 4) void gemm_kernel(const float* __restrict__ xnT,
                                                      const ushort* __restrict__ Bp,
                                                      float* __restrict__ partials) {
  constexpr int BK = 32;
  __shared__ __align__(16) ushort As[128 * BK];   // 8 KB
  __shared__ __align__(16) ushort Bs[128 * BK];   // 8 KB

  // swizzle: all 8 col-blocks of one (row,kz) slab land on the same XCD (id%8 heuristic)
  const int id  = blockIdx.x;
  const int xcd = id & 7;
  const int q   = id >> 3;            // 0..127
  const int col = q & 7;
  const int pr  = xcd * 16 + (q >> 3);  // 0..127 unique (row,kz) pair
  const int row = pr >> 1;
  const int kz  = pr & 1;             // K-split half
  const int rowBase = row * 128;
  const int colBase = col * 128;

  const int t    = threadIdx.x;
  const int wave = t >> 6;
  const int lane = t & 63;
  const int wr   = wave >> 1;
  const int wc   = wave & 1;
  const int c16  = lane & 15;
  const int quad = lane >> 4;

  // B staging: thread t -> rows colBase+(t>>2) and +64, k-chunk (t&3)*8
  const int srow = t >> 2;
  const int skc  = (t & 3) * 8;
  const ushort* bptr0 = Bp + (size_t)(colBase + srow) * KTIL + kz * 8192 + skc;
  const ushort* bptr1 = bptr0 + (size_t)64 * KTIL;
  ushort* lB0 = &Bs[t * 8];
  ushort* lB1 = &Bs[2048 + t * 8];

  // A build: thread t owns (r = t&127, il = t>>7); i = kz*512 + ip*2 + il
  const int ar = t & 127;
  const int ail = t >> 7;
  const float* xp = xnT + (size_t)(kz * 512 + ail) * BROWS + rowBase + ar;
  ushort* aw = &As[ar * BK + ail * KP];

  f32x4 acc[4][4];
#pragma unroll
  for (int a = 0; a < 4; ++a)
#pragma unroll
    for (int b = 0; b < 4; ++b) acc[a][b] = (f32x4){0.f, 0.f, 0.f, 0.f};

  for (int ip = 0; ip < 256; ++ip) {
    const float xn = xp[(size_t)ip * 2 * BROWS];   // coalesced over 128 lanes
    __syncthreads();                               // prev tile fully consumed
    gload_lds16(bptr0 + ip * BK, lB0);
    gload_lds16(bptr1 + ip * BK, lB1);
    // Chebyshev T_0..T_8 in fp32, pack to bf16 pairs, 32 B -> LDS
    {
      float T0 = 1.0f, T1 = xn;
      uint w0 = 0x3f80u | ((uint)f2bf(xn) << 16);  // pack(1.0, xn)
      float T2 = 2.f * xn * T1 - T0;
      float T3 = 2.f * xn * T2 - T1;
      uint w1 = (uint)f2bf(T2) | ((uint)f2bf(T3) << 16);
      float T4 = 2.f * xn * T3 - T2;
      float T5 = 2.f * xn * T4 - T3;
      uint w2 = (uint)f2bf(T4) | ((uint)f2bf(T5) << 16);
      float T6 = 2.f * xn * T5 - T4;
      float T7 = 2.f * xn * T6 - T5;
      uint w3 = (uint)f2bf(T6) | ((uint)f2bf(T7) << 16);
      float T8 = 2.f * xn * T7 - T6;
      uint w4 = (uint)f2bf(T8);                    // high half zero (pad)
      *(uint4*)aw       = (uint4){w0, w1, w2, w3};
      *(uint4*)(aw + 8) = (uint4){w4, 0u, 0u, 0u}; // pad slots 10..15 zero
    }
    __syncthreads();                               // drains vmcnt + lgkmcnt

    bf16x8s afr[4], bfr[4];
#pragma unroll
    for (int tm = 0; tm < 4; ++tm)                 // A frag: m = lane&15, k = quad*8+j
      afr[tm] = *(const bf16x8s*)&As[(wr * 64 + tm * 16 + c16) * BK + quad * 8];
#pragma unroll
    for (int tn = 0; tn < 4; ++tn)                 // B frag: n = lane&15, k = quad*8+j
      bfr[tn] = *(const bf16x8s*)&Bs[(wc * 64 + tn * 16 + c16) * BK + quad * 8];
#pragma unroll
    for (int tm = 0; tm < 4; ++tm)
#pragma unroll
      for (int tn = 0; tn < 4; ++tn)
        acc[tm][tn] = __builtin_amdgcn_mfma_f32_16x16x32_bf16(afr[tm], bfr[tn],
                                                              acc[tm][tn], 0, 0, 0);
  }

  // epilogue -> fp32 partials[kz]; C/D mapping col = lane&15, row = quad*4 + r
  float* pout = partials + (size_t)kz * (BROWS * ODIM);
#pragma unroll
  for (int tm = 0; tm < 4; ++tm)
#pragma unroll
    for (int tn = 0; tn < 4; ++tn) {
      const int row0 = rowBase + wr * 64 + tm * 16 + quad * 4;
      const int colo = colBase + wc * 64 + tn * 16 + c16;
#pragma unroll
      for (int r = 0; r < 4; ++r)
        pout[(size_t)(row0 + r) * ODIM + colo] = acc[tm][tn][r];
    }
}

// ---------- 5. out = partials[0] + partials[1] ----------
__global__ __launch_bounds__(256) void reduce_kernel(const float4* __restrict__ p,
                                                     float4* __restrict__ out) {
  const int idx = blockIdx.x * 256 + threadIdx.x;
  const float4 a = p[idx];
  const float4 b = p[idx + (BROWS * ODIM / 4)];
  out[idx] = (float4){a.x + b.x, a.y + b.y, a.z + b.z, a.w + b.w};
}

extern "C" void kernel_launch(void* const* d_in, const int* in_sizes, int n_in,
                              void* d_out, int out_size, void* d_ws, size_t ws_size,
                              hipStream_t stream) {
  const float* x      = (const float*)d_in[0];   // [8192,1024] fp32
  const float* coeffs = (const float*)d_in[1];   // [1024,1024,9] fp32
  float* out = (float*)d_out;                    // [8192,1024] fp32

  char* ws = (char*)d_ws;
  float*  stats    = (float*)ws;                                        // 64 KB
  float*  xnT      = (float*)(ws + 65536);                              // 32 MB
  ushort* Bp       = (ushort*)(ws + 65536 + (size_t)IDIM * BROWS * 4);  // 33.5 MB
  float*  partials = (float*)(ws + 65536 + (size_t)IDIM * BROWS * 4
                                        + (size_t)ODIM * KTIL * 2);     // 67 MB

  rowstats_kernel<<<BROWS / 4, 256, 0, stream>>>(x, stats);
  transpose_norm_kernel<<<dim3(IDIM / 64, BROWS / 64), 256, 0, stream>>>(x, stats, xnT);
  build_b_kernel<<<dim3(IDIM / 16, ODIM / 64), 256, 0, stream>>>(coeffs, Bp);
  gemm_kernel<<<1024, 256, 0, stream>>>(xnT, Bp, partials);
  reduce_kernel<<<BROWS * ODIM / 4 / 256, 256, 0, stream>>>((const float4*)partials,
                                                            (float4*)out);
}

// Round 4
// 358.013 us; speedup vs baseline: 1.3219x; 1.3219x over previous
//
#include <hip/hip_runtime.h>
#include <hip/hip_bf16.h>

// ChebyshevKANLayer: y[b,o] = sum_{i,j} T_j(xhat[b,i]) * C[i,o,j]
//   == GEMM  M=8192, N=1024, K=1024*9=9216 (unpadded), bf16 in, fp32 acc.
// R4: R2 structure + split-K x2 (grid 1024 = 4 blocks/CU) + BK=64 (32 MFMA per
// barrier-pair) + XOR-swizzled LDS columns (bank-conflict-free frag reads).
// ws: [0,64K) stats | [+18.9MB) B^T bf16 [O][K] | [+151MB) A bf16 [M][K] |
//     [+32MB) partial fp32 (kz=1 half)

typedef __attribute__((ext_vector_type(8))) short bf16x8s;   // MFMA A/B frag (4 VGPRs)
typedef __attribute__((ext_vector_type(4))) float f32x4;     // MFMA C/D frag

constexpr int BROWS = 8192;
constexpr int IDIM  = 1024;
constexpr int ODIM  = 1024;
constexpr int DEG1  = 9;
constexpr int KDIM  = IDIM * DEG1;   // 9216
constexpr int KHALF = KDIM / 2;      // 4608 (multiple of 64)

__device__ __forceinline__ ushort f2bf(float f) {
  return ((__hip_bfloat16_raw)__float2bfloat16(f)).x;
}

// async global->LDS, 16 B per lane. LDS dst MUST be wave-uniform base + lane*16.
__device__ __forceinline__ void gload_lds16(const void* g, void* l) {
  __builtin_amdgcn_global_load_lds(
      (const __attribute__((address_space(1))) unsigned int*)g,
      (__attribute__((address_space(3))) unsigned int*)l, 16, 0, 0);
}

// ---------- 1. per-row min/max -> (scale, offset):  xhat = scale*x + offset ----------
__global__ __launch_bounds__(256) void rowstats_kernel(const float* __restrict__ x,
                                                       float* __restrict__ stats) {
  const int row  = blockIdx.x * 4 + (threadIdx.x >> 6);   // one wave per row
  const int lane = threadIdx.x & 63;
  const float4* xr = (const float4*)(x + (size_t)row * IDIM);
  float mn = 3.402823466e38f, mx = -3.402823466e38f;
#pragma unroll
  for (int c = 0; c < 4; ++c) {
    float4 v = xr[lane + c * 64];
    mn = fminf(mn, fminf(fminf(v.x, v.y), fminf(v.z, v.w)));
    mx = fmaxf(mx, fmaxf(fmaxf(v.x, v.y), fmaxf(v.z, v.w)));
  }
#pragma unroll
  for (int off = 32; off >= 1; off >>= 1) {
    mn = fminf(mn, __shfl_xor(mn, off));
    mx = fmaxf(mx, __shfl_xor(mx, off));
  }
  if (lane == 0) {
    float inv = 2.0f / (mx - mn);
    stats[row * 2 + 0] = inv;                 // scale
    stats[row * 2 + 1] = -mn * inv - 1.0f;    // offset
  }
}

// ---------- 2. A[b][i*9+j] = T_j(xhat[b,i]) bf16; LDS repack -> uint4 coalesced writes ----
__global__ __launch_bounds__(256) void build_a_kernel(const float* __restrict__ x,
                                                      const float* __restrict__ stats,
                                                      __hip_bfloat16* __restrict__ A2) {
  __shared__ __align__(16) ushort Arow[KDIM];              // 18 KB: one full A row
  const int b = blockIdx.x;
  const int t = threadIdx.x;
  const float sc = stats[b * 2 + 0];
  const float of = stats[b * 2 + 1];
#pragma unroll
  for (int c = 0; c < 4; ++c) {
    const int i = c * 256 + t;
    const float xn = fmaf(sc, x[(size_t)b * IDIM + i], of);
    float T0 = 1.0f, T1 = xn;
    ushort* dst = Arow + i * DEG1;
    dst[0] = f2bf(1.0f);
    dst[1] = f2bf(xn);
#pragma unroll
    for (int n = 2; n < DEG1; ++n) {
      float Tn = 2.0f * xn * T1 - T0;
      dst[n] = f2bf(Tn);
      T0 = T1; T1 = Tn;
    }
  }
  __syncthreads();
  uint4* gdst = (uint4*)(A2 + (size_t)b * KDIM);           // 1152 uint4, coalesced
  const uint4* lsrc = (const uint4*)Arow;
  for (int idx = t; idx < KDIM / 8; idx += 256) gdst[idx] = lsrc[idx];
}

// ---------- 3. B^T[o][i*9+j] = C[i][o][j] bf16; LDS transpose tile ----------
__global__ __launch_bounds__(256) void build_b_kernel(const float* __restrict__ coeffs,
                                                      __hip_bfloat16* __restrict__ B2T) {
  __shared__ __align__(16) ushort tile[64 * 288];          // 36 KB  [o_l][i_l*9+j]
  const int i0 = blockIdx.x * 32;
  const int o0 = blockIdx.y * 64;
  const int t  = threadIdx.x;
  for (int idx = t; idx < 18432; idx += 256) {             // coalesced float reads
    const int i_l = idx / 576;                             // 576 = 64*9
    const int rem = idx - i_l * 576;                       // = o_l*9 + j
    const float v = coeffs[((size_t)(i0 + i_l) * ODIM + o0) * DEG1 + rem];
    const int o_l = rem / 9;
    const int j   = rem - o_l * 9;
    tile[o_l * 288 + i_l * DEG1 + j] = f2bf(v);
  }
  __syncthreads();
  for (int idx = t; idx < 2304; idx += 256) {              // coalesced uint4 writes
    const int o_l = idx / 36;
    const int w   = idx - o_l * 36;
    uint4* gdst = (uint4*)((ushort*)B2T + (size_t)(o0 + o_l) * KDIM + i0 * DEG1);
    gdst[w] = ((const uint4*)tile)[idx];
  }
}

// ---------- 4. GEMM: 128x128 tile, BK=64, split-K x2, swizzled LDS ----------
// LDS layout: row stride 64 ushorts (128 B); 16B chunk at physical col
// p = logical_col ^ (row & 7).  Staging permutes the GLOBAL chunk each lane
// fetches so lane-linear LDS placement realizes this swizzle.
__global__ __launch_bounds__(256, 4) void gemm_kernel(const ushort* __restrict__ A2,
                                                      const ushort* __restrict__ B2T,
                                                      float* __restrict__ out0,
                                                      float* __restrict__ part1) {
  constexpr int BK = 64;
  __shared__ __align__(16) ushort As[128 * BK];   // 16 KB
  __shared__ __align__(16) ushort Bs[128 * BK];   // 16 KB

  const int t    = threadIdx.x;
  const int wave = t >> 6;
  const int lane = t & 63;
  const int wr   = wave >> 1;
  const int wc   = wave & 1;
  const int c16  = lane & 15;
  const int quad = lane >> 4;
  const int rowBase = blockIdx.y * 128;
  const int colBase = blockIdx.x * 128;
  const int kz      = blockIdx.z;                 // K-split half

  // staging: rep rr covers rows rr*32 + (t>>3); global col chunk is XOR-permuted
  const int srow = t >> 3;                        // 0..31
  const int scol = (t & 7) ^ (srow & 7);          // permuted within 128B segment
  const ushort* aB = A2  + (size_t)(rowBase + srow) * KDIM + (size_t)kz * KHALF + scol * 8;
  const ushort* bB = B2T + (size_t)(colBase + srow) * KDIM + (size_t)kz * KHALF + scol * 8;
  ushort* lA = &As[t * 8];                        // lane-linear (wave-uniform + lane*16)
  ushort* lB = &Bs[t * 8];

  f32x4 acc[4][4];
#pragma unroll
  for (int a = 0; a < 4; ++a)
#pragma unroll
    for (int b = 0; b < 4; ++b) acc[a][b] = (f32x4){0.f, 0.f, 0.f, 0.f};

  for (int ip = 0; ip < KHALF / BK; ++ip) {       // 72 iters
    const size_t ko = (size_t)ip * BK;
    __syncthreads();                              // prev tile fully consumed
#pragma unroll
    for (int rr = 0; rr < 4; ++rr) {
      gload_lds16(aB + (size_t)rr * 32 * KDIM + ko, lA + rr * 2048);
      gload_lds16(bB + (size_t)rr * 32 * KDIM + ko, lB + rr * 2048);
    }
    __syncthreads();                              // drains vmcnt -> tile visible

#pragma unroll
    for (int kh = 0; kh < 2; ++kh) {              // sequential k-halves: low VGPR
      const int cx = ((kh * 4 + quad) ^ (c16 & 7)) * 8;   // swizzled col, bytes/2
      bf16x8s afr[4], bfr[4];
#pragma unroll
      for (int tm = 0; tm < 4; ++tm)              // A frag: m = lane&15, k = quad*8+j
        afr[tm] = *(const bf16x8s*)&As[(wr * 64 + tm * 16 + c16) * BK + cx];
#pragma unroll
      for (int tn = 0; tn < 4; ++tn)
        bfr[tn] = *(const bf16x8s*)&Bs[(wc * 64 + tn * 16 + c16) * BK + cx];
#pragma unroll
      for (int tm = 0; tm < 4; ++tm)
#pragma unroll
        for (int tn = 0; tn < 4; ++tn)
          acc[tm][tn] = __builtin_amdgcn_mfma_f32_16x16x32_bf16(afr[tm], bfr[tn],
                                                                acc[tm][tn], 0, 0, 0);
    }
  }

  // epilogue: kz=0 -> out, kz=1 -> partial.  C/D map: col = lane&15, row = quad*4+r
  float* pout = kz ? part1 : out0;
#pragma unroll
  for (int tm = 0; tm < 4; ++tm)
#pragma unroll
    for (int tn = 0; tn < 4; ++tn) {
      const int row0 = rowBase + wr * 64 + tm * 16 + quad * 4;
      const int colo = colBase + wc * 64 + tn * 16 + c16;
#pragma unroll
      for (int r = 0; r < 4; ++r)
        pout[(size_t)(row0 + r) * ODIM + colo] = acc[tm][tn][r];
    }
}

// ---------- 5. out += partial ----------
__global__ __launch_bounds__(256) void reduce_kernel(float4* __restrict__ out,
                                                     const float4* __restrict__ p1) {
  const int idx = blockIdx.x * 256 + threadIdx.x;
  const float4 a = out[idx];
  const float4 b = p1[idx];
  out[idx] = (float4){a.x + b.x, a.y + b.y, a.z + b.z, a.w + b.w};
}

extern "C" void kernel_launch(void* const* d_in, const int* in_sizes, int n_in,
                              void* d_out, int out_size, void* d_ws, size_t ws_size,
                              hipStream_t stream) {
  const float* x      = (const float*)d_in[0];   // [8192,1024] fp32
  const float* coeffs = (const float*)d_in[1];   // [1024,1024,9] fp32
  float* out = (float*)d_out;                    // [8192,1024] fp32

  char* ws = (char*)d_ws;
  float*  stats = (float*)ws;                                           // 64 KB
  ushort* B2T   = (ushort*)(ws + 65536);                                // 18.87 MB
  ushort* A2    = (ushort*)(ws + 65536 + (size_t)ODIM * KDIM * 2);      // 151 MB
  float*  part1 = (float*)(ws + 65536 + (size_t)ODIM * KDIM * 2
                                      + (size_t)BROWS * KDIM * 2);      // 32 MB
  // total ws: ~203.6 MB

  rowstats_kernel<<<BROWS / 4, 256, 0, stream>>>(x, stats);
  build_a_kernel<<<BROWS, 256, 0, stream>>>(x, stats, (__hip_bfloat16*)A2);
  build_b_kernel<<<dim3(IDIM / 32, ODIM / 64), 256, 0, stream>>>(coeffs,
                                                                 (__hip_bfloat16*)B2T);
  gemm_kernel<<<dim3(ODIM / 128, BROWS / 128, 2), 256, 0, stream>>>(A2, B2T, out, part1);
  reduce_kernel<<<BROWS * ODIM / 4 / 256, 256, 0, stream>>>((float4*)out,
                                                            (const float4*)part1);
}

// Round 5
// 320.830 us; speedup vs baseline: 1.4751x; 1.1159x over previous
//
#include <hip/hip_runtime.h>
#include <hip/hip_bf16.h>

// ChebyshevKANLayer: y[b,o] = sum_{i,j} T_j(xhat[b,i]) * C[i,o,j]
//   == GEMM  M=8192, N=1024, K=9216, bf16 in, fp32 acc.
// R5: R4 GEMM loop kept verbatim, but split-K moved IN-BLOCK (512 thr, 8 waves,
// two 4-wave k-half groups, epilogue combine via LDS) -> no reduce kernel, no
// part1. rowstats fused into build_a. ws: B^T 18.9MB | A 151MB.

typedef __attribute__((ext_vector_type(8))) short bf16x8s;   // MFMA A/B frag (4 VGPRs)
typedef __attribute__((ext_vector_type(4))) float f32x4;     // MFMA C/D frag

constexpr int BROWS = 8192;
constexpr int IDIM  = 1024;
constexpr int ODIM  = 1024;
constexpr int DEG1  = 9;
constexpr int KDIM  = IDIM * DEG1;   // 9216
constexpr int KHALF = KDIM / 2;      // 4608 (multiple of 64)

__device__ __forceinline__ ushort f2bf(float f) {
  return ((__hip_bfloat16_raw)__float2bfloat16(f)).x;
}

// async global->LDS, 16 B per lane. LDS dst MUST be wave-uniform base + lane*16.
__device__ __forceinline__ void gload_lds16(const void* g, void* l) {
  __builtin_amdgcn_global_load_lds(
      (const __attribute__((address_space(1))) unsigned int*)g,
      (__attribute__((address_space(3))) unsigned int*)l, 16, 0, 0);
}

// ---------- 1. fused rowstats + A-build: A[b][i*9+j] = T_j(xhat[b,i]) bf16 ----------
__global__ __launch_bounds__(256) void build_a_kernel(const float* __restrict__ x,
                                                      __hip_bfloat16* __restrict__ A2) {
  __shared__ __align__(16) ushort Arow[KDIM];              // 18 KB
  __shared__ float red[8];
  const int b = blockIdx.x, t = threadIdx.x, lane = t & 63, wv = t >> 6;
  const float4 v = ((const float4*)(x + (size_t)b * IDIM))[t];   // i = 4t..4t+3
  float mn = fminf(fminf(v.x, v.y), fminf(v.z, v.w));
  float mx = fmaxf(fmaxf(v.x, v.y), fmaxf(v.z, v.w));
#pragma unroll
  for (int off = 32; off >= 1; off >>= 1) {
    mn = fminf(mn, __shfl_xor(mn, off));
    mx = fmaxf(mx, __shfl_xor(mx, off));
  }
  if (lane == 0) { red[wv] = mn; red[4 + wv] = mx; }
  __syncthreads();
  mn = fminf(fminf(red[0], red[1]), fminf(red[2], red[3]));
  mx = fmaxf(fmaxf(red[4], red[5]), fmaxf(red[6], red[7]));
  const float sc = 2.0f / (mx - mn);
  const float of = -mn * sc - 1.0f;

  const float xs[4] = {v.x, v.y, v.z, v.w};
  ushort h[36];                                            // static indices -> regs
#pragma unroll
  for (int c = 0; c < 4; ++c) {
    const float xn = fmaf(sc, xs[c], of);
    float T0 = 1.0f, T1 = xn;
    h[c * 9 + 0] = f2bf(1.0f);
    h[c * 9 + 1] = f2bf(xn);
#pragma unroll
    for (int n = 2; n < DEG1; ++n) {
      const float Tn = 2.0f * xn * T1 - T0;
      h[c * 9 + n] = f2bf(Tn);
      T0 = T1; T1 = Tn;
    }
  }
  uint2* d64 = (uint2*)(Arow + t * 36);                    // 72B/thread, 8B-aligned
#pragma unroll
  for (int k = 0; k < 9; ++k)
    d64[k] = (uint2){(uint)h[4 * k] | ((uint)h[4 * k + 1] << 16),
                     (uint)h[4 * k + 2] | ((uint)h[4 * k + 3] << 16)};
  __syncthreads();
  uint4* gdst = (uint4*)(A2 + (size_t)b * KDIM);           // 1152 uint4, coalesced
  const uint4* lsrc = (const uint4*)Arow;
  for (int idx = t; idx < KDIM / 8; idx += 256) gdst[idx] = lsrc[idx];
}

// ---------- 2. B^T[o][i*9+j] = C[i][o][j] bf16; LDS transpose tile ----------
__global__ __launch_bounds__(256) void build_b_kernel(const float* __restrict__ coeffs,
                                                      __hip_bfloat16* __restrict__ B2T) {
  __shared__ __align__(16) ushort tile[64 * 288];          // 36 KB  [o_l][i_l*9+j]
  const int i0 = blockIdx.x * 32;
  const int o0 = blockIdx.y * 64;
  const int t  = threadIdx.x;
  for (int idx = t; idx < 18432; idx += 256) {             // coalesced float reads
    const int i_l = idx / 576;                             // 576 = 64*9
    const int rem = idx - i_l * 576;                       // = o_l*9 + j
    const float v = coeffs[((size_t)(i0 + i_l) * ODIM + o0) * DEG1 + rem];
    const int o_l = rem / 9;
    const int j   = rem - o_l * 9;
    tile[o_l * 288 + i_l * DEG1 + j] = f2bf(v);
  }
  __syncthreads();
  for (int idx = t; idx < 2304; idx += 256) {              // coalesced uint4 writes
    const int o_l = idx / 36;
    const int w   = idx - o_l * 36;
    uint4* gdst = (uint4*)((ushort*)B2T + (size_t)(o0 + o_l) * KDIM + i0 * DEG1);
    gdst[w] = ((const uint4*)tile)[idx];
  }
}

// ---------- 3. GEMM: 128x128 tile, BK=64, IN-BLOCK split-K x2, swizzled LDS ----------
// 512 threads = 8 waves; group g = wave>>2 handles k-half g with its own As/Bs
// region (4 x 16 KB = 64 KB). Epilogue: group 1 parks its acc in LDS (reusing
// the staging space as a 128x128 fp32 Ctile), group 0 adds and stores.
__global__ __launch_bounds__(512, 4) void gemm_kernel(const ushort* __restrict__ A2,
                                                      const ushort* __restrict__ B2T,
                                                      float* __restrict__ out) {
  constexpr int BK = 64;
  __shared__ __align__(16) ushort Sm[32768];      // 64 KB total
  const int t    = threadIdx.x;
  const int wave = t >> 6;
  const int lane = t & 63;
  const int g    = wave >> 2;                     // k-half group 0/1
  const int w4   = wave & 3;
  const int wr   = w4 >> 1;
  const int wc   = w4 & 1;
  const int c16  = lane & 15;
  const int quad = lane >> 4;
  const int rowBase = blockIdx.y * 128;
  const int colBase = blockIdx.x * 128;           // id%8 = col -> one B-slab per XCD

  ushort* As = Sm + g * 8192;                     // [128][64] ushort, 16 KB
  ushort* Bs = Sm + 16384 + g * 8192;

  // staging (group-local 256 threads): rep rr covers rows rr*32 + (tp>>3);
  // global col chunk XOR-permuted so lane-linear LDS realizes the swizzle.
  const int tp   = t & 255;
  const int srow = tp >> 3;                       // 0..31
  const int scol = (tp & 7) ^ (srow & 7);
  const ushort* aB = A2  + (size_t)(rowBase + srow) * KDIM + (size_t)g * KHALF + scol * 8;
  const ushort* bB = B2T + (size_t)(colBase + srow) * KDIM + (size_t)g * KHALF + scol * 8;
  ushort* lA = As + tp * 8;                       // wave-uniform base + lane*16B
  ushort* lB = Bs + tp * 8;

  f32x4 acc[4][4];
#pragma unroll
  for (int a = 0; a < 4; ++a)
#pragma unroll
    for (int b = 0; b < 4; ++b) acc[a][b] = (f32x4){0.f, 0.f, 0.f, 0.f};

  for (int ip = 0; ip < KHALF / BK; ++ip) {       // 72 iters
    const size_t ko = (size_t)ip * BK;
    __syncthreads();                              // prev tile fully consumed
#pragma unroll
    for (int rr = 0; rr < 4; ++rr) {
      gload_lds16(aB + (size_t)rr * 32 * KDIM + ko, lA + rr * 2048);
      gload_lds16(bB + (size_t)rr * 32 * KDIM + ko, lB + rr * 2048);
    }
    __syncthreads();                              // drains vmcnt -> tile visible

#pragma unroll
    for (int kh = 0; kh < 2; ++kh) {              // sequential k-halves: low VGPR
      const int cx = ((kh * 4 + quad) ^ (c16 & 7)) * 8;   // swizzled col
      bf16x8s afr[4], bfr[4];
#pragma unroll
      for (int tm = 0; tm < 4; ++tm)              // A frag: m = lane&15, k = quad*8+j
        afr[tm] = *(const bf16x8s*)&As[(wr * 64 + tm * 16 + c16) * BK + cx];
#pragma unroll
      for (int tn = 0; tn < 4; ++tn)
        bfr[tn] = *(const bf16x8s*)&Bs[(wc * 64 + tn * 16 + c16) * BK + cx];
#pragma unroll
      for (int tm = 0; tm < 4; ++tm)
#pragma unroll
        for (int tn = 0; tn < 4; ++tn)
          acc[tm][tn] = __builtin_amdgcn_mfma_f32_16x16x32_bf16(afr[tm], bfr[tn],
                                                                acc[tm][tn], 0, 0, 0);
    }
  }

  // ---- epilogue: combine the two k-halves through LDS, single out write ----
  __syncthreads();                                // all frag reads done; Sm reusable
  float* Ct = (float*)Sm;                         // 128x128 fp32 = 64 KB
  if (g == 1) {
#pragma unroll
    for (int tm = 0; tm < 4; ++tm)
#pragma unroll
      for (int tn = 0; tn < 4; ++tn) {
        const int lr0 = wr * 64 + tm * 16 + quad * 4;
        const int cl  = wc * 64 + tn * 16 + c16;
#pragma unroll
        for (int r = 0; r < 4; ++r) Ct[(lr0 + r) * 128 + cl] = acc[tm][tn][r];
      }
  }
  __syncthreads();
  if (g == 0) {
#pragma unroll
    for (int tm = 0; tm < 4; ++tm)
#pragma unroll
      for (int tn = 0; tn < 4; ++tn) {
        const int lr0 = wr * 64 + tm * 16 + quad * 4;
        const int cl  = wc * 64 + tn * 16 + c16;
#pragma unroll
        for (int r = 0; r < 4; ++r)
          out[(size_t)(rowBase + lr0 + r) * ODIM + colBase + cl] =
              acc[tm][tn][r] + Ct[(lr0 + r) * 128 + cl];
      }
  }
}

extern "C" void kernel_launch(void* const* d_in, const int* in_sizes, int n_in,
                              void* d_out, int out_size, void* d_ws, size_t ws_size,
                              hipStream_t stream) {
  const float* x      = (const float*)d_in[0];   // [8192,1024] fp32
  const float* coeffs = (const float*)d_in[1];   // [1024,1024,9] fp32
  float* out = (float*)d_out;                    // [8192,1024] fp32

  char* ws = (char*)d_ws;
  ushort* B2T = (ushort*)ws;                                        // 18.87 MB
  ushort* A2  = (ushort*)(ws + (size_t)ODIM * KDIM * 2);            // 151 MB
  // total ws: ~170 MB

  build_a_kernel<<<BROWS, 256, 0, stream>>>(x, (__hip_bfloat16*)A2);
  build_b_kernel<<<dim3(IDIM / 32, ODIM / 64), 256, 0, stream>>>(coeffs,
                                                                 (__hip_bfloat16*)B2T);
  gemm_kernel<<<dim3(ODIM / 128, BROWS / 128), 512, 0, stream>>>(A2, B2T, out);
}

// Round 6
// 315.018 us; speedup vs baseline: 1.5024x; 1.0185x over previous
//
#include <hip/hip_runtime.h>
#include <hip/hip_bf16.h>

// ChebyshevKANLayer: y[b,o] = sum_{i,j} T_j(xhat[b,i]) * C[i,o,j]
// R6: T0==1 folded into an fp32 bias vector (bias[o] = sum_i C[i,o,0]) ->
// GEMM K = 1024*8 = 8192 (degrees 1..8). Every (b,i) A-entry is exactly one
// uint4 -> build_a needs NO LDS repack (coalesced 16B/lane stores).
// GEMM: 128x128 tile, BK=64, in-block split-K x2 (512 thr), XOR-swizzled LDS,
// global_load_lds(16B) staging. ws: bias 4KB | B^T 16.8MB | A 134MB.

typedef __attribute__((ext_vector_type(8))) short bf16x8s;   // MFMA A/B frag (4 VGPRs)
typedef __attribute__((ext_vector_type(4))) float f32x4;     // MFMA C/D frag

constexpr int BROWS = 8192;
constexpr int IDIM  = 1024;
constexpr int ODIM  = 1024;
constexpr int DEG1  = 9;
constexpr int KP    = 8;             // stored degrees 1..8 per input i
constexpr int KD    = IDIM * KP;     // 8192
constexpr int KH    = KD / 2;        // 4096

__device__ __forceinline__ ushort f2bf(float f) {
  return ((__hip_bfloat16_raw)__float2bfloat16(f)).x;
}

// async global->LDS, 16 B per lane. LDS dst MUST be wave-uniform base + lane*16.
__device__ __forceinline__ void gload_lds16(const void* g, void* l) {
  __builtin_amdgcn_global_load_lds(
      (const __attribute__((address_space(1))) unsigned int*)g,
      (__attribute__((address_space(3))) unsigned int*)l, 16, 0, 0);
}

// ---------- 0. zero the bias accumulator (ws is poisoned every call) ----------
__global__ __launch_bounds__(256) void zero_bias_kernel(float* __restrict__ bias) {
  bias[blockIdx.x * 256 + threadIdx.x] = 0.0f;
}

// ---------- 1. fused rowstats + A-build: A[b][i*8+d'] = T_{d'+1}(xhat) bf16 ----------
// No LDS repack: each (b,i) is one uint4; thread t writes offset (c*256+t)*16 B
// -> perfectly coalesced. Row stats via shuffle + tiny LDS reduce.
__global__ __launch_bounds__(256) void build_a_kernel(const float* __restrict__ x,
                                                      ushort* __restrict__ A2) {
  __shared__ float red[8];
  const int b = blockIdx.x, t = threadIdx.x, lane = t & 63, wv = t >> 6;
  const float* xr = x + (size_t)b * IDIM;
  const float4 v = ((const float4*)xr)[t];                 // i = 4t..4t+3
  float mn = fminf(fminf(v.x, v.y), fminf(v.z, v.w));
  float mx = fmaxf(fmaxf(v.x, v.y), fmaxf(v.z, v.w));
#pragma unroll
  for (int off = 32; off >= 1; off >>= 1) {
    mn = fminf(mn, __shfl_xor(mn, off));
    mx = fmaxf(mx, __shfl_xor(mx, off));
  }
  if (lane == 0) { red[wv] = mn; red[4 + wv] = mx; }
  __syncthreads();
  mn = fminf(fminf(red[0], red[1]), fminf(red[2], red[3]));
  mx = fmaxf(fmaxf(red[4], red[5]), fmaxf(red[6], red[7]));
  const float sc = 2.0f / (mx - mn);
  const float of = -mn * sc - 1.0f;

  uint4* adst = (uint4*)(A2 + (size_t)b * KD);
#pragma unroll
  for (int c = 0; c < 4; ++c) {
    const int i = c * 256 + t;                             // lanes consecutive
    const float xn = fmaf(sc, xr[i], of);                  // L1-hot re-read
    const float T2 = 2.f * xn * xn - 1.f;
    const float T3 = 2.f * xn * T2 - xn;
    const float T4 = 2.f * xn * T3 - T2;
    const float T5 = 2.f * xn * T4 - T3;
    const float T6 = 2.f * xn * T5 - T4;
    const float T7 = 2.f * xn * T6 - T5;
    const float T8 = 2.f * xn * T7 - T6;
    uint4 w;
    w.x = (uint)f2bf(xn) | ((uint)f2bf(T2) << 16);         // d' 0,1 = T1,T2
    w.y = (uint)f2bf(T3) | ((uint)f2bf(T4) << 16);
    w.z = (uint)f2bf(T5) | ((uint)f2bf(T6) << 16);
    w.w = (uint)f2bf(T7) | ((uint)f2bf(T8) << 16);
    adst[i] = w;                                           // coalesced 16 B/lane
  }
}

// ---------- 2. B^T[o][i*8+d'] = C[i][o][d'+1] bf16; j==0 -> fp32 bias ----------
__global__ __launch_bounds__(256) void build_b_kernel(const float* __restrict__ coeffs,
                                                      ushort* __restrict__ B2T,
                                                      float* __restrict__ bias) {
  __shared__ __align__(16) ushort tile[64 * 256];          // 32 KB [o_l][i_l*8+d']
  __shared__ float lb[64];
  const int i0 = blockIdx.x * 32;
  const int o0 = blockIdx.y * 64;
  const int t  = threadIdx.x;
  if (t < 64) lb[t] = 0.0f;
  __syncthreads();
  for (int idx = t; idx < 18432; idx += 256) {             // coalesced float reads
    const int i_l = idx / 576;                             // 576 = 64*9
    const int rem = idx - i_l * 576;                       // = o_l*9 + j
    const float v = coeffs[((size_t)(i0 + i_l) * ODIM + o0) * DEG1 + rem];
    const int o_l = rem / 9;
    const int j   = rem - o_l * 9;
    if (j == 0) atomicAdd(&lb[o_l], v);                    // exact fp32 bias path
    else tile[o_l * 256 + i_l * KP + (j - 1)] = f2bf(v);
  }
  __syncthreads();
  for (int idx = t; idx < 2048; idx += 256) {              // coalesced uint4 writes
    const int o_l = idx >> 5;
    const int w   = idx & 31;
    uint4* gdst = (uint4*)(B2T + (size_t)(o0 + o_l) * KD + i0 * KP);
    gdst[w] = ((const uint4*)tile)[idx];
  }
  if (t < 64) atomicAdd(&bias[o0 + t], lb[t]);             // device-scope fp32 add
}

// ---------- 3. GEMM: 128x128 tile, BK=64, IN-BLOCK split-K x2, swizzled LDS ----------
// 512 threads = 8 waves; group g = wave>>2 handles k-half g with its own As/Bs
// region (64 KB). Epilogue: group 1 parks acc in LDS (Sm reused as fp32 Ctile),
// group 0 adds, adds bias[col], stores.
__global__ __launch_bounds__(512, 4) void gemm_kernel(const ushort* __restrict__ A2,
                                                      const ushort* __restrict__ B2T,
                                                      const float* __restrict__ bias,
                                                      float* __restrict__ out) {
  constexpr int BK = 64;
  __shared__ __align__(16) ushort Sm[32768];      // 64 KB total
  const int t    = threadIdx.x;
  const int wave = t >> 6;
  const int lane = t & 63;
  const int g    = wave >> 2;                     // k-half group 0/1
  const int w4   = wave & 3;
  const int wr   = w4 >> 1;
  const int wc   = w4 & 1;
  const int c16  = lane & 15;
  const int quad = lane >> 4;
  const int rowBase = blockIdx.y * 128;
  const int colBase = blockIdx.x * 128;           // id%8 = col -> one B-slab per XCD

  ushort* As = Sm + g * 8192;                     // [128][64] ushort, 16 KB
  ushort* Bs = Sm + 16384 + g * 8192;

  // staging (group-local 256 threads): rep rr covers rows rr*32 + (tp>>3);
  // global col chunk XOR-permuted so lane-linear LDS realizes the swizzle.
  const int tp   = t & 255;
  const int srow = tp >> 3;                       // 0..31
  const int scol = (tp & 7) ^ (srow & 7);
  const ushort* aB = A2  + (size_t)(rowBase + srow) * KD + (size_t)g * KH + scol * 8;
  const ushort* bB = B2T + (size_t)(colBase + srow) * KD + (size_t)g * KH + scol * 8;
  ushort* lA = As + tp * 8;                       // wave-uniform base + lane*16B
  ushort* lB = Bs + tp * 8;

  f32x4 acc[4][4];
#pragma unroll
  for (int a = 0; a < 4; ++a)
#pragma unroll
    for (int b = 0; b < 4; ++b) acc[a][b] = (f32x4){0.f, 0.f, 0.f, 0.f};

  for (int ip = 0; ip < KH / BK; ++ip) {          // 64 iters
    const size_t ko = (size_t)ip * BK;
    __syncthreads();                              // prev tile fully consumed
#pragma unroll
    for (int rr = 0; rr < 4; ++rr) {
      gload_lds16(aB + (size_t)rr * 32 * KD + ko, lA + rr * 2048);
      gload_lds16(bB + (size_t)rr * 32 * KD + ko, lB + rr * 2048);
    }
    __syncthreads();                              // drains vmcnt -> tile visible

#pragma unroll
    for (int kh = 0; kh < 2; ++kh) {              // sequential k-halves: low VGPR
      const int cx = ((kh * 4 + quad) ^ (c16 & 7)) * 8;   // swizzled col
      bf16x8s afr[4], bfr[4];
#pragma unroll
      for (int tm = 0; tm < 4; ++tm)              // A frag: m = lane&15, k = quad*8+j
        afr[tm] = *(const bf16x8s*)&As[(wr * 64 + tm * 16 + c16) * BK + cx];
#pragma unroll
      for (int tn = 0; tn < 4; ++tn)
        bfr[tn] = *(const bf16x8s*)&Bs[(wc * 64 + tn * 16 + c16) * BK + cx];
#pragma unroll
      for (int tm = 0; tm < 4; ++tm)
#pragma unroll
        for (int tn = 0; tn < 4; ++tn)
          acc[tm][tn] = __builtin_amdgcn_mfma_f32_16x16x32_bf16(afr[tm], bfr[tn],
                                                                acc[tm][tn], 0, 0, 0);
    }
  }

  // ---- epilogue: combine k-halves through LDS, add bias, single out write ----
  __syncthreads();                                // all frag reads done; Sm reusable
  float* Ct = (float*)Sm;                         // 128x128 fp32 = 64 KB
  if (g == 1) {
#pragma unroll
    for (int tm = 0; tm < 4; ++tm)
#pragma unroll
      for (int tn = 0; tn < 4; ++tn) {
        const int lr0 = wr * 64 + tm * 16 + quad * 4;
        const int cl  = wc * 64 + tn * 16 + c16;
#pragma unroll
        for (int r = 0; r < 4; ++r) Ct[(lr0 + r) * 128 + cl] = acc[tm][tn][r];
      }
  }
  __syncthreads();
  if (g == 0) {
#pragma unroll
    for (int tm = 0; tm < 4; ++tm)
#pragma unroll
      for (int tn = 0; tn < 4; ++tn) {
        const int lr0 = wr * 64 + tm * 16 + quad * 4;
        const int cl  = wc * 64 + tn * 16 + c16;
        const float bv = bias[colBase + cl];
#pragma unroll
        for (int r = 0; r < 4; ++r)
          out[(size_t)(rowBase + lr0 + r) * ODIM + colBase + cl] =
              acc[tm][tn][r] + Ct[(lr0 + r) * 128 + cl] + bv;
      }
  }
}

extern "C" void kernel_launch(void* const* d_in, const int* in_sizes, int n_in,
                              void* d_out, int out_size, void* d_ws, size_t ws_size,
                              hipStream_t stream) {
  const float* x      = (const float*)d_in[0];   // [8192,1024] fp32
  const float* coeffs = (const float*)d_in[1];   // [1024,1024,9] fp32
  float* out = (float*)d_out;                    // [8192,1024] fp32

  char* ws = (char*)d_ws;
  float*  bias = (float*)ws;                                        // 4 KB (pad 64K)
  ushort* B2T  = (ushort*)(ws + 65536);                             // 16.78 MB
  ushort* A2   = (ushort*)(ws + 65536 + (size_t)ODIM * KD * 2);     // 134.2 MB
  // total ws: ~151 MB

  zero_bias_kernel<<<ODIM / 256, 256, 0, stream>>>(bias);
  build_a_kernel<<<BROWS, 256, 0, stream>>>(x, A2);
  build_b_kernel<<<dim3(IDIM / 32, ODIM / 64), 256, 0, stream>>>(coeffs, B2T, bias);
  gemm_kernel<<<dim3(ODIM / 128, BROWS / 128), 512, 0, stream>>>(A2, B2T, bias, out);
}